// Round 1
// baseline (604.685 us; speedup 1.0000x reference)
//
#include <hip/hip_runtime.h>
#include <math.h>

#define BATCH 2
#define SEQ   2048
#define NH    64
#define HD    64
#define DS    128
#define CS    256
#define NC    8   // SEQ/CS

// ---------------------------------------------------------------------------
// K1: dt softplus + dA cumsum.  grid = B*NH*NC blocks of CS threads.
// dtp/dacs layout: ((b*NH+h)*NC+c)*CS + s
// ---------------------------------------------------------------------------
__global__ __launch_bounds__(CS) void k1_dt(
    const float* __restrict__ dt, const float* __restrict__ A,
    const float* __restrict__ dt_bias,
    float* __restrict__ dtp, float* __restrict__ dacs)
{
    int bid = blockIdx.x;                 // ((b*NH+h)*NC+c)
    int c = bid % NC;
    int h = (bid / NC) % NH;
    int b = bid / (NC * NH);
    int s = threadIdx.x;

    float v  = dt[((size_t)b * SEQ + c * CS + s) * NH + h] + dt_bias[h];
    // softplus = logaddexp(v, 0), numerically stable
    float sp = fmaxf(v, 0.f) + log1pf(__expf(-fabsf(v)));
    float dA = sp * A[h];

    __shared__ float sm[CS];
    sm[s] = dA;
    __syncthreads();
    for (int off = 1; off < CS; off <<= 1) {
        float t = (s >= off) ? sm[s - off] : 0.f;
        __syncthreads();
        sm[s] += t;
        __syncthreads();
    }
    size_t o = (size_t)bid * CS + s;
    dtp[o]  = sp;
    dacs[o] = sm[s];
}

// ---------------------------------------------------------------------------
// K2: CB[b,c,l,s] = sum_n C[b,c*CS+l,n] * B[b,c*CS+s,n]  (ngroups==1)
// grid = B*NC*16 blocks (4x4 tiles of 64x64), 256 threads.
// ---------------------------------------------------------------------------
__global__ __launch_bounds__(256) void k2_cb(
    const float* __restrict__ Bg_, const float* __restrict__ Cg_,
    float* __restrict__ cb)
{
    int bid = blockIdx.x;
    int ts = bid & 3;
    int tl = (bid >> 2) & 3;
    int bc = bid >> 4;                    // b*NC + c
    int b = bc / NC, c = bc % NC;

    const float* Cg = Cg_ + (size_t)(b * SEQ + c * CS + tl * 64) * DS;
    const float* Bg = Bg_ + (size_t)(b * SEQ + c * CS + ts * 64) * DS;

    __shared__ __align__(16) float Ct[32][68];   // [n][l]
    __shared__ __align__(16) float Bt[32][68];   // [n][s]

    int t  = threadIdx.x;
    int tx = t & 15, ty = t >> 4;
    int s0 = tx * 4, l0 = ty * 4;
    float acc[4][4] = {};

    for (int n0 = 0; n0 < DS; n0 += 32) {
        __syncthreads();
        {
            int r  = t >> 5;              // 0..7
            int nn = t & 31;
            #pragma unroll
            for (int i = 0; i < 8; ++i) {
                Ct[nn][r + i * 8] = Cg[(size_t)(r + i * 8) * DS + n0 + nn];
                Bt[nn][r + i * 8] = Bg[(size_t)(r + i * 8) * DS + n0 + nn];
            }
        }
        __syncthreads();
        #pragma unroll 8
        for (int n = 0; n < 32; ++n) {
            float4 cv = *(const float4*)&Ct[n][l0];
            float4 bv = *(const float4*)&Bt[n][s0];
            float cva[4] = {cv.x, cv.y, cv.z, cv.w};
            float bva[4] = {bv.x, bv.y, bv.z, bv.w};
            #pragma unroll
            for (int i = 0; i < 4; ++i)
                #pragma unroll
                for (int j = 0; j < 4; ++j)
                    acc[i][j] += cva[i] * bva[j];
        }
    }

    float* cbg = cb + (size_t)bc * CS * CS;
    #pragma unroll
    for (int i = 0; i < 4; ++i) {
        *(float4*)&cbg[(size_t)(tl * 64 + l0 + i) * CS + ts * 64 + s0] =
            make_float4(acc[i][0], acc[i][1], acc[i][2], acc[i][3]);
    }
}

// ---------------------------------------------------------------------------
// K3: chunk_state. states[b,c,h,p,n] = sum_s B[s,n]*exp(daL-dacs[s])*dt[s]*x[s,p]
// grid = B*NC*NH blocks ((b*NC+c)*NH+h), 256 threads, 8p x 4n per thread.
// ---------------------------------------------------------------------------
__global__ __launch_bounds__(256) void k3_chunk_state(
    const float* __restrict__ x, const float* __restrict__ Bg_,
    const float* __restrict__ dtp, const float* __restrict__ dacs,
    float* __restrict__ states)
{
    int bid = blockIdx.x;                 // ((b*NC+c)*NH + h)
    int h = bid % NH;
    int c = (bid / NH) % NC;
    int b = bid / (NH * NC);

    int t  = threadIdx.x;
    int tx = t & 31, ty = t >> 5;
    int n0 = tx * 4, p0 = ty * 8;

    size_t dt_base = ((size_t)(b * NH + h) * NC + c) * CS;
    float da_last  = dacs[dt_base + CS - 1];

    __shared__ __align__(16) float xs[32 * 64];
    __shared__ __align__(16) float Bs[32 * 128];
    __shared__ float co[32];

    float acc[8][4] = {};
    const float* xg = x   + ((size_t)(b * SEQ + c * CS) * NH + h) * HD;
    const float* Bg = Bg_ + (size_t)(b * SEQ + c * CS) * DS;

    for (int s0 = 0; s0 < CS; s0 += 32) {
        __syncthreads();
        #pragma unroll
        for (int i = 0; i < 8; ++i) {
            int flat = t + i * 256;
            int sr = flat >> 6, p = flat & 63;
            xs[flat] = xg[(size_t)(s0 + sr) * NH * HD + p];
        }
        #pragma unroll
        for (int i = 0; i < 16; ++i) {
            int flat = t + i * 256;
            int sr = flat >> 7, n = flat & 127;
            Bs[flat] = Bg[(size_t)(s0 + sr) * DS + n];
        }
        if (t < 32)
            co[t] = __expf(da_last - dacs[dt_base + s0 + t]) * dtp[dt_base + s0 + t];
        __syncthreads();

        #pragma unroll 4
        for (int sr = 0; sr < 32; ++sr) {
            float  cvx = co[sr];
            float4 bv  = *(const float4*)&Bs[sr * 128 + n0];
            float4 xa  = *(const float4*)&xs[sr * 64 + p0];
            float4 xb  = *(const float4*)&xs[sr * 64 + p0 + 4];
            float xv[8] = {xa.x, xa.y, xa.z, xa.w, xb.x, xb.y, xb.z, xb.w};
            #pragma unroll
            for (int i = 0; i < 8; ++i) {
                float xc = xv[i] * cvx;
                acc[i][0] += xc * bv.x;
                acc[i][1] += xc * bv.y;
                acc[i][2] += xc * bv.z;
                acc[i][3] += xc * bv.w;
            }
        }
    }

    float* sg = states + (size_t)bid * HD * DS;
    #pragma unroll
    for (int i = 0; i < 8; ++i) {
        *(float4*)&sg[(size_t)(p0 + i) * DS + n0] =
            make_float4(acc[i][0], acc[i][1], acc[i][2], acc[i][3]);
    }
}

// ---------------------------------------------------------------------------
// K4: state_passing. In-place states -> prev_states, plus final_states.
// grid = B*NH*HD*DS / 256 blocks.
// ---------------------------------------------------------------------------
__global__ __launch_bounds__(256) void k4_state_passing(
    float* __restrict__ states, const float* __restrict__ dacs,
    float* __restrict__ final_states)
{
    int e = blockIdx.x * 256 + threadIdx.x;   // over B*NH*HD*DS
    int n = e % DS;
    int p = (e / DS) % HD;
    int h = (e / (DS * HD)) % NH;
    int b = e / (DS * HD * NH);

    float r = 0.f;
    #pragma unroll
    for (int c = 0; c < NC; ++c) {
        size_t idx = (((size_t)(b * NC + c) * NH + h) * HD + p) * DS + n;
        float v = states[idx];
        states[idx] = r;                       // prev_states
        float dal = dacs[((size_t)(b * NH + h) * NC + c) * CS + CS - 1];
        r = __expf(dal) * r + v;
    }
    final_states[((size_t)(b * NH + h) * HD + p) * DS + n] = r;
}

// ---------------------------------------------------------------------------
// K5: chunk_scan + epilogue.
// grid = B*NC*NH*4 blocks (((b*NC+c)*NH+h)*4 + lt), 256 threads.
// Per thread: 2 l-rows x 8 p-cols.
// ---------------------------------------------------------------------------
__global__ __launch_bounds__(256) void k5_chunk_scan(
    const float* __restrict__ x, const float* __restrict__ z,
    const float* __restrict__ Cg_, const float* __restrict__ Dp,
    const float* __restrict__ dtp, const float* __restrict__ dacs,
    const float* __restrict__ cb, const float* __restrict__ prev,
    float* __restrict__ out)
{
    int bid = blockIdx.x;
    int lt = bid & 3;
    int bch = bid >> 2;                   // (b*NC+c)*NH + h
    int h = bch % NH;
    int c = (bch / NH) % NC;
    int b = bch / (NH * NC);

    int l0 = lt * 64;
    int t  = threadIdx.x;
    int tx = t & 7, ty = t >> 3;
    int p0 = tx * 8;
    int lA = l0 + ty * 2;
    int lB = lA + 1;

    size_t dt_base = ((size_t)(b * NH + h) * NC + c) * CS;
    float dalA = dacs[dt_base + lA];
    float dalB = dacs[dt_base + lB];
    size_t cb_base = (size_t)(b * NC + c) * CS * CS;

    __shared__ __align__(16) float smem[8320];
    float* xdt = smem;                    // 64*64
    float* cbt = smem + 4096;             // 64*65
    float* dss = smem + 4096 + 4160;      // 64

    float acc1[2][8] = {};
    const float* xg = x + ((size_t)(b * SEQ + c * CS) * NH + h) * HD;

    // ---- phase B: intra-chunk masked scan ----
    int nst = lt + 1;
    for (int st = 0; st < nst; ++st) {
        int s0 = st * 64;
        __syncthreads();
        #pragma unroll
        for (int i = 0; i < 16; ++i) {
            int flat = t + i * 256;
            int sr = flat >> 6, p = flat & 63;
            xdt[flat] = xg[(size_t)(s0 + sr) * NH * HD + p] * dtp[dt_base + s0 + sr];
        }
        #pragma unroll
        for (int i = 0; i < 16; ++i) {
            int flat = t + i * 256;
            int lr = flat >> 6, sc = flat & 63;
            cbt[lr * 65 + sc] = cb[cb_base + (size_t)(l0 + lr) * CS + s0 + sc];
        }
        if (t < 64) dss[t] = dacs[dt_base + s0 + t];
        __syncthreads();

        #pragma unroll 4
        for (int sr = 0; sr < 64; ++sr) {
            int s = s0 + sr;
            float dsv = dss[sr];
            float4 xa = *(const float4*)&xdt[sr * 64 + p0];
            float4 xb = *(const float4*)&xdt[sr * 64 + p0 + 4];
            float cbA = cbt[(ty * 2) * 65 + sr];
            float cbB = cbt[(ty * 2 + 1) * 65 + sr];
            // mask BEFORE exp so we never form inf (exp of +huge) then 0*inf
            float argA = (s <= lA) ? (dalA - dsv) : -1e30f;
            float argB = (s <= lB) ? (dalB - dsv) : -1e30f;
            float wA = cbA * __expf(argA);
            float wB = cbB * __expf(argB);
            float xv[8] = {xa.x, xa.y, xa.z, xa.w, xb.x, xb.y, xb.z, xb.w};
            #pragma unroll
            for (int j = 0; j < 8; ++j) {
                acc1[0][j] += wA * xv[j];
                acc1[1][j] += wB * xv[j];
            }
        }
    }

    // ---- phase A: inter-chunk state term: sum_n C[l,n]*prev[p,n] ----
    float acc2[2][8] = {};
    float* Ct = smem;                     // [32][68]  [n][l]
    float* Pt = smem + 32 * 68;           // [32][68]  [n][p]
    const float* Cgp = Cg_ + (size_t)(b * SEQ + c * CS + l0) * DS;
    const float* pg  = prev + ((size_t)(b * NC + c) * NH + h) * HD * DS;

    for (int nt = 0; nt < 4; ++nt) {
        int n0 = nt * 32;
        __syncthreads();
        {
            int nn = t & 31;
            int r0 = t >> 5;              // 0..7
            #pragma unroll
            for (int i = 0; i < 8; ++i) {
                int r = r0 + i * 8;       // row 0..63 (l for Ct, p for Pt)
                Ct[nn * 68 + r] = Cgp[(size_t)r * DS + n0 + nn];
                Pt[nn * 68 + r] = pg[(size_t)r * DS + n0 + nn];
            }
        }
        __syncthreads();
        #pragma unroll 8
        for (int n = 0; n < 32; ++n) {
            float2 cv = *(const float2*)&Ct[n * 68 + ty * 2];
            float4 pa = *(const float4*)&Pt[n * 68 + p0];
            float4 pb = *(const float4*)&Pt[n * 68 + p0 + 4];
            float pv[8] = {pa.x, pa.y, pa.z, pa.w, pb.x, pb.y, pb.z, pb.w};
            #pragma unroll
            for (int j = 0; j < 8; ++j) {
                acc2[0][j] += cv.x * pv[j];
                acc2[1][j] += cv.y * pv[j];
            }
        }
    }

    // ---- epilogue: decay*state-term + D residual, SiLU(z) gate ----
    float elA = __expf(dalA), elB = __expf(dalB);
    float Dh  = Dp[h];
    size_t orow = ((size_t)(b * SEQ + c * CS) * NH + h) * HD;
    const float* xg0 = x + orow;
    const float* zg0 = z + orow;
    float* og0 = out + orow;

    #pragma unroll
    for (int i = 0; i < 2; ++i) {
        int l = lA + i;                   // chunk-local row
        float el = i ? elB : elA;
        size_t rb = (size_t)l * NH * HD + p0;
        #pragma unroll
        for (int jv = 0; jv < 2; ++jv) {
            float4 xv = *(const float4*)&xg0[rb + jv * 4];
            float4 zv = *(const float4*)&zg0[rb + jv * 4];
            float xvv[4] = {xv.x, xv.y, xv.z, xv.w};
            float zvv[4] = {zv.x, zv.y, zv.z, zv.w};
            float ov[4];
            #pragma unroll
            for (int k = 0; k < 4; ++k) {
                float o = acc1[i][jv * 4 + k] + acc2[i][jv * 4 + k] * el + xvv[k] * Dh;
                float sig = 1.f / (1.f + __expf(-zvv[k]));
                ov[k] = o * (zvv[k] * sig);
            }
            *(float4*)&og0[rb + jv * 4] = make_float4(ov[0], ov[1], ov[2], ov[3]);
        }
    }
}

// ---------------------------------------------------------------------------
extern "C" void kernel_launch(void* const* d_in, const int* in_sizes, int n_in,
                              void* d_out, int out_size, void* d_ws, size_t ws_size,
                              hipStream_t stream)
{
    (void)in_sizes; (void)n_in; (void)out_size; (void)ws_size;
    const float* x       = (const float*)d_in[0];
    const float* dt      = (const float*)d_in[1];
    const float* A       = (const float*)d_in[2];
    const float* B       = (const float*)d_in[3];
    const float* C       = (const float*)d_in[4];
    const float* D       = (const float*)d_in[5];
    const float* z       = (const float*)d_in[6];
    const float* dt_bias = (const float*)d_in[7];

    float* out           = (float*)d_out;
    float* final_states  = out + (size_t)BATCH * SEQ * NH * HD;

    float* ws     = (float*)d_ws;
    float* dtp    = ws;                                   // B*NH*NC*CS   = 262144
    float* dacs   = dtp    + (size_t)BATCH * NH * NC * CS;
    float* states = dacs   + (size_t)BATCH * NH * NC * CS; // B*NC*NH*HD*DS = 8388608
    float* cb     = states + (size_t)BATCH * NC * NH * HD * DS; // B*NC*CS*CS = 1048576

    k1_dt<<<BATCH * NH * NC, CS, 0, stream>>>(dt, A, dt_bias, dtp, dacs);
    k2_cb<<<BATCH * NC * 16, 256, 0, stream>>>(B, C, cb);
    k3_chunk_state<<<BATCH * NC * NH, 256, 0, stream>>>(x, B, dtp, dacs, states);
    k4_state_passing<<<(BATCH * NH * HD * DS) / 256, 256, 0, stream>>>(states, dacs, final_states);
    k5_chunk_scan<<<BATCH * NC * NH * 4, 256, 0, stream>>>(x, z, C, D, dtp, dacs, cb, states, out);
}

// Round 4
// 398.292 us; speedup vs baseline: 1.5182x; 1.5182x over previous
//
#include <hip/hip_runtime.h>
#include <math.h>

#define BATCH 2
#define SEQ   2048
#define NH    64
#define HD    64
#define DS    128
#define CS    256
#define NC    8   // SEQ/CS

typedef __attribute__((ext_vector_type(8))) short s16x8;   // 8 bf16 (4 VGPR)
typedef __attribute__((ext_vector_type(4))) float f32x4;   // 16x16 acc

#define MFMA16(a,b,c) __builtin_amdgcn_mfma_f32_16x16x32_bf16(a, b, c, 0, 0, 0)

// explicit RNE f32->bf16
__device__ inline unsigned short f2bf(float f) {
    unsigned u = __float_as_uint(f);
    return (unsigned short)((u + (0x7fffu + ((u >> 16) & 1u))) >> 16);
}
__device__ inline unsigned pack2bf(float a, float b) {
    return (unsigned)f2bf(a) | ((unsigned)f2bf(b) << 16);
}
__device__ inline float2 unpack2bf(unsigned u) {
    return make_float2(__uint_as_float(u << 16), __uint_as_float(u & 0xffff0000u));
}

// ---------------------------------------------------------------------------
// K0a: x[b,s,h,p] f32 -> xT[(b,c,h), p, s] bf16 (s contiguous). 1024 blocks.
// ---------------------------------------------------------------------------
__global__ __launch_bounds__(256) void k0a_xT(
    const float* __restrict__ x, unsigned* __restrict__ xT)
{
    int bid = blockIdx.x;             // ((b*NC+c)*NH+h)
    int h = bid & 63, c = (bid >> 6) & 7, b = bid >> 9;
    int t = threadIdx.x;
    __shared__ float tile[64][65];
    for (int st = 0; st < 4; ++st) {
        int s0 = st * 64;
        __syncthreads();
        #pragma unroll
        for (int i = 0; i < 16; ++i) {
            int f = t + i * 256;
            int row = f >> 6, col = f & 63;
            tile[row][col] = x[((size_t)(b*SEQ + c*CS + s0 + row)*NH + h)*HD + col];
        }
        __syncthreads();
        #pragma unroll
        for (int i = 0; i < 8; ++i) {
            int f = t + i * 256;
            int p = f >> 5, sd = f & 31;
            xT[((size_t)bid*64 + p)*128 + (s0 >> 1) + sd] =
                pack2bf(tile[2*sd][p], tile[2*sd+1][p]);
        }
    }
}

// ---------------------------------------------------------------------------
// K0b: flat f32 -> packed bf16 cast (for C). 256 blocks x 256 thr x 8 elems.
// ---------------------------------------------------------------------------
__global__ __launch_bounds__(256) void k0b_cast(
    const float* __restrict__ src, unsigned* __restrict__ dst)
{
    size_t f = (size_t)blockIdx.x * 256 + threadIdx.x;
    const float4* s4 = (const float4*)(src + f * 8);
    float4 a = s4[0], bq = s4[1];
    uint4 o;
    o.x = pack2bf(a.x,  a.y);  o.y = pack2bf(a.z,  a.w);
    o.z = pack2bf(bq.x, bq.y); o.w = pack2bf(bq.z, bq.w);
    *(uint4*)(dst + f * 4) = o;
}

// ---------------------------------------------------------------------------
// K0c: B[b,s,n] f32 -> BT[(b,c), n, s] bf16. 128 blocks (bc*8 + nt*4 + st).
// ---------------------------------------------------------------------------
__global__ __launch_bounds__(256) void k0c_BT(
    const float* __restrict__ Bg, unsigned* __restrict__ BT)
{
    int bid = blockIdx.x;
    int st = bid & 3, nt = (bid >> 2) & 1, bc = bid >> 3;
    int b = bc >> 3, c = bc & 7;
    int s0 = st * 64, n0 = nt * 64;
    int t = threadIdx.x;
    __shared__ float tile[64][65];
    #pragma unroll
    for (int i = 0; i < 16; ++i) {
        int f = t + i * 256;
        int row = f >> 6, col = f & 63;
        tile[row][col] = Bg[(size_t)(b*SEQ + c*CS + s0 + row)*DS + n0 + col];
    }
    __syncthreads();
    #pragma unroll
    for (int i = 0; i < 8; ++i) {
        int f = t + i * 256;
        int n = f >> 5, sd = f & 31;
        BT[((size_t)bc*128 + n0 + n)*128 + (s0 >> 1) + sd] =
            pack2bf(tile[2*sd][n], tile[2*sd+1][n]);
    }
}

// ---------------------------------------------------------------------------
// K1: dt softplus + dA cumsum (fp32).  dtp/dacs: ((b*NH+h)*NC+c)*CS + s
// ---------------------------------------------------------------------------
__global__ __launch_bounds__(CS) void k1_dt(
    const float* __restrict__ dt, const float* __restrict__ A,
    const float* __restrict__ dt_bias,
    float* __restrict__ dtp, float* __restrict__ dacs)
{
    int bid = blockIdx.x;                 // ((b*NH+h)*NC+c)
    int c = bid % NC;
    int h = (bid / NC) % NH;
    int b = bid / (NC * NH);
    int s = threadIdx.x;

    float v  = dt[((size_t)b * SEQ + c * CS + s) * NH + h] + dt_bias[h];
    float sp = fmaxf(v, 0.f) + log1pf(__expf(-fabsf(v)));
    float dA = sp * A[h];

    __shared__ float sm[CS];
    sm[s] = dA;
    __syncthreads();
    for (int off = 1; off < CS; off <<= 1) {
        float tt = (s >= off) ? sm[s - off] : 0.f;
        __syncthreads();
        sm[s] += tt;
        __syncthreads();
    }
    size_t o = (size_t)bid * CS + s;
    dtp[o]  = sp;
    dacs[o] = sm[s];
}

// ---------------------------------------------------------------------------
// K2: CB tiles (fp32 VALU compute, bf16 packed output). Only tl >= ts tiles.
// grid = B*NC*10.
// ---------------------------------------------------------------------------
__global__ __launch_bounds__(256) void k2_cb(
    const float* __restrict__ Bg_, const float* __restrict__ Cg_,
    unsigned* __restrict__ cb_bf)
{
    const int TLt[10] = {0,1,1,2,2,2,3,3,3,3};
    const int TSt[10] = {0,0,1,0,1,2,0,1,2,3};
    int bid = blockIdx.x;
    int ti = bid % 10;
    int bc = bid / 10;
    int tl = TLt[ti], ts = TSt[ti];
    int b = bc / NC, c = bc % NC;

    const float* Cg = Cg_ + (size_t)(b * SEQ + c * CS + tl * 64) * DS;
    const float* Bg = Bg_ + (size_t)(b * SEQ + c * CS + ts * 64) * DS;

    __shared__ __align__(16) float Ct[32][68];
    __shared__ __align__(16) float Bt[32][68];

    int t  = threadIdx.x;
    int tx = t & 15, ty = t >> 4;
    int s0 = tx * 4, l0 = ty * 4;
    float acc[4][4] = {};

    for (int n0 = 0; n0 < DS; n0 += 32) {
        __syncthreads();
        {
            int r  = t >> 5;
            int nn = t & 31;
            #pragma unroll
            for (int i = 0; i < 8; ++i) {
                Ct[nn][r + i * 8] = Cg[(size_t)(r + i * 8) * DS + n0 + nn];
                Bt[nn][r + i * 8] = Bg[(size_t)(r + i * 8) * DS + n0 + nn];
            }
        }
        __syncthreads();
        #pragma unroll 8
        for (int n = 0; n < 32; ++n) {
            float4 cv = *(const float4*)&Ct[n][l0];
            float4 bv = *(const float4*)&Bt[n][s0];
            float cva[4] = {cv.x, cv.y, cv.z, cv.w};
            float bva[4] = {bv.x, bv.y, bv.z, bv.w};
            #pragma unroll
            for (int i = 0; i < 4; ++i)
                #pragma unroll
                for (int j = 0; j < 4; ++j)
                    acc[i][j] += cva[i] * bva[j];
        }
    }

    unsigned* cbg = cb_bf + (size_t)bc * 32768;   // 256*128 dwords
    #pragma unroll
    for (int i = 0; i < 4; ++i) {
        int row  = tl * 64 + l0 + i;
        int colb = (ts * 64 + s0) >> 1;
        uint2 wv;
        wv.x = pack2bf(acc[i][0], acc[i][1]);
        wv.y = pack2bf(acc[i][2], acc[i][3]);
        *(uint2*)&cbg[(size_t)row * 128 + colb] = wv;
    }
}

// ---------------------------------------------------------------------------
// K3: chunk_state via 16x16x32 MFMA.
// ---------------------------------------------------------------------------
__global__ __launch_bounds__(256) void k3_chunk_state(
    const unsigned* __restrict__ xT, const unsigned* __restrict__ BT,
    const float* __restrict__ dtp, const float* __restrict__ dacs,
    float* __restrict__ states)
{
    int bid = blockIdx.x;                 // ((b*NC+c)*NH+h)
    int bc = bid >> 6;
    int h = bid & 63, c = (bid >> 6) & 7, b = bid >> 9;
    int t = threadIdx.x;
    int w = t >> 6, lane = t & 63, m16 = lane & 15, q = lane >> 4;

    size_t dt_base = ((size_t)(b*NH + h)*NC + c)*CS;
    float daL = dacs[dt_base + CS - 1];

    __shared__ unsigned xwS[64 * 36];     // [p][s-pairs], row stride 36 dw
    __shared__ unsigned btS[128 * 36];    // [n][s-pairs]
    __shared__ float coS[64];

    f32x4 acc[8] = {};

    for (int ks = 0; ks < 4; ++ks) {
        int s0 = ks * 64;
        __syncthreads();
        if (t < 64)
            coS[t] = dtp[dt_base + s0 + t] * __expf(daL - dacs[dt_base + s0 + t]);
        #pragma unroll
        for (int i = 0; i < 16; ++i) {
            int f = t + i * 256;
            int n = f >> 5, sd = f & 31;
            btS[n * 36 + sd] = BT[((size_t)bc*128 + n)*128 + (s0 >> 1) + sd];
        }
        __syncthreads();
        #pragma unroll
        for (int i = 0; i < 8; ++i) {
            int f = t + i * 256;
            int p = f >> 5, sd = f & 31;
            float2 v = unpack2bf(xT[((size_t)bid*64 + p)*128 + (s0 >> 1) + sd]);
            xwS[p * 36 + sd] = pack2bf(v.x * coS[2*sd], v.y * coS[2*sd + 1]);
        }
        __syncthreads();
        #pragma unroll
        for (int kk = 0; kk < 2; ++kk) {
            int kd = kk * 16 + q * 4;     // dword offset: bf16 k = 32*kk + 8*q
            s16x8 af = *(const s16x8*)&xwS[(w*16 + m16)*36 + kd];
            #pragma unroll
            for (int nt = 0; nt < 8; ++nt) {
                s16x8 bfr = *(const s16x8*)&btS[(nt*16 + m16)*36 + kd];
                acc[nt] = MFMA16(af, bfr, acc[nt]);
            }
        }
    }

    float* sg = states + (size_t)bid * (HD * DS);
    #pragma unroll
    for (int nt = 0; nt < 8; ++nt) {
        #pragma unroll
        for (int r = 0; r < 4; ++r) {
            int p = w*16 + q*4 + r;
            sg[(size_t)p * 128 + nt*16 + m16] = acc[nt][r];
        }
    }
}

// ---------------------------------------------------------------------------
// K4: state_passing (fp32, in place states -> prev) + final_states.
// ---------------------------------------------------------------------------
__global__ __launch_bounds__(256) void k4_state_passing(
    float* __restrict__ states, const float* __restrict__ dacs,
    float* __restrict__ final_states)
{
    int e = blockIdx.x * 256 + threadIdx.x;
    int n = e % DS;
    int p = (e / DS) % HD;
    int h = (e / (DS * HD)) % NH;
    int b = e / (DS * HD * NH);

    float r = 0.f;
    #pragma unroll
    for (int c = 0; c < NC; ++c) {
        size_t idx = (((size_t)(b * NC + c) * NH + h) * HD + p) * DS + n;
        float v = states[idx];
        states[idx] = r;
        float dal = dacs[((size_t)(b * NH + h) * NC + c) * CS + CS - 1];
        r = __expf(dal) * r + v;
    }
    final_states[((size_t)(b * NH + h) * HD + p) * DS + n] = r;
}

// ---------------------------------------------------------------------------
// K5: chunk_scan via 16x16x32 MFMA. Phase A decay folded into staged C.
// ---------------------------------------------------------------------------
__global__ __launch_bounds__(256) void k5_chunk_scan(
    const float* __restrict__ x, const float* __restrict__ z,
    const unsigned* __restrict__ Cb, const float* __restrict__ Dp,
    const float* __restrict__ dtp, const float* __restrict__ dacs,
    const unsigned* __restrict__ cb_bf, const unsigned* __restrict__ xT,
    const float* __restrict__ prev, float* __restrict__ out)
{
    int bid = blockIdx.x;                 // ((b*NC+c)*NH+h)
    int h = bid & 63, c = (bid >> 6) & 7, b = bid >> 9;
    int bc = bid >> 6;
    int t = threadIdx.x;
    int w = t >> 6, lane = t & 63, m16 = lane & 15, q = lane >> 4;

    __shared__ unsigned Ws[256 * 36];
    __shared__ unsigned Xs[64 * 36];
    __shared__ float dacsS[CS], dtpS[CS], elS[CS];

    size_t dt_base = ((size_t)(b*NH + h)*NC + c)*CS;
    {
        float dv = dacs[dt_base + t];
        dacsS[t] = dv;
        elS[t]   = __expf(dv);
        dtpS[t]  = dtp[dt_base + t];
    }

    f32x4 acc[4][4] = {};                 // [lt][pt]

    // ---- phase B: intra-chunk masked scan ----
    for (int st = 0; st < 4; ++st) {
        int s0 = st * 64;
        int rows = 256 - s0;
        __syncthreads();
        for (int f = t; f < rows * 32; f += 256) {
            int r = f >> 5, sd = f & 31;
            int l = s0 + r;
            float2 v = unpack2bf(cb_bf[(size_t)bc*32768 + (size_t)l*128 + (s0 >> 1) + sd]);
            float dl = dacsS[l];
            int s = s0 + 2*sd;
            float w0 = (s     <= l) ? v.x * __expf(dl - dacsS[s])     * dtpS[s]     : 0.f;
            float w1 = (s + 1 <= l) ? v.y * __expf(dl - dacsS[s + 1]) * dtpS[s + 1] : 0.f;
            Ws[r * 36 + sd] = pack2bf(w0, w1);
        }
        #pragma unroll
        for (int i = 0; i < 8; ++i) {
            int f = t + i * 256;
            int p = f >> 5, sd = f & 31;
            Xs[p * 36 + sd] = xT[((size_t)bid*64 + p)*128 + (s0 >> 1) + sd];
        }
        __syncthreads();
        if (w >= st) {
            #pragma unroll
            for (int kk = 0; kk < 2; ++kk) {
                int kd = kk * 16 + q * 4;
                s16x8 bfr[4];
                #pragma unroll
                for (int pt = 0; pt < 4; ++pt)
                    bfr[pt] = *(const s16x8*)&Xs[(pt*16 + m16)*36 + kd];
                #pragma unroll
                for (int lt = 0; lt < 4; ++lt) {
                    s16x8 af = *(const s16x8*)&Ws[((w - st)*64 + lt*16 + m16)*36 + kd];
                    #pragma unroll
                    for (int pt = 0; pt < 4; ++pt)
                        acc[lt][pt] = MFMA16(af, bfr[pt], acc[lt][pt]);
                }
            }
        }
    }

    // ---- phase A: inter-chunk term, decay folded into C ----
    for (int kn = 0; kn < 2; ++kn) {
        __syncthreads();
        #pragma unroll
        for (int i = 0; i < 32; ++i) {
            int f = t + i * 256;
            int r = f >> 5, nd = f & 31;
            float2 v = unpack2bf(Cb[(size_t)(b*SEQ + c*CS + r)*64 + kn*32 + nd]);
            float el = elS[r];
            Ws[r * 36 + nd] = pack2bf(v.x * el, v.y * el);
        }
        #pragma unroll
        for (int i = 0; i < 8; ++i) {
            int f = t + i * 256;
            int p = f >> 5, nd = f & 31;
            float2 pv = *(const float2*)&prev[(size_t)bid*8192 + (size_t)p*128 + kn*64 + 2*nd];
            Xs[p * 36 + nd] = pack2bf(pv.x, pv.y);
        }
        __syncthreads();
        #pragma unroll
        for (int kk = 0; kk < 2; ++kk) {
            int kd = kk * 16 + q * 4;
            s16x8 bfr[4];
            #pragma unroll
            for (int pt = 0; pt < 4; ++pt)
                bfr[pt] = *(const s16x8*)&Xs[(pt*16 + m16)*36 + kd];
            #pragma unroll
            for (int lt = 0; lt < 4; ++lt) {
                s16x8 af = *(const s16x8*)&Ws[(w*64 + lt*16 + m16)*36 + kd];
                #pragma unroll
                for (int pt = 0; pt < 4; ++pt)
                    acc[lt][pt] = MFMA16(af, bfr[pt], acc[lt][pt]);
            }
        }
    }

    // ---- epilogue: + x*D, SiLU(z) gate ----
    float Dh = Dp[h];
    #pragma unroll
    for (int lt = 0; lt < 4; ++lt) {
        #pragma unroll
        for (int r = 0; r < 4; ++r) {
            int l = w*64 + lt*16 + q*4 + r;
            size_t gro = ((size_t)(b*SEQ + c*CS + l)*NH + h)*HD;
            #pragma unroll
            for (int pt = 0; pt < 4; ++pt) {
                int p = pt*16 + m16;
                float xv = x[gro + p], zv = z[gro + p];
                float o = acc[lt][pt][r] + xv * Dh;
                float sig = 1.f / (1.f + __expf(-zv));
                out[gro + p] = o * (zv * sig);
            }
        }
    }
}

// ---------------------------------------------------------------------------
extern "C" void kernel_launch(void* const* d_in, const int* in_sizes, int n_in,
                              void* d_out, int out_size, void* d_ws, size_t ws_size,
                              hipStream_t stream)
{
    (void)in_sizes; (void)n_in; (void)out_size; (void)ws_size;
    const float* x       = (const float*)d_in[0];
    const float* dt      = (const float*)d_in[1];
    const float* A       = (const float*)d_in[2];
    const float* B       = (const float*)d_in[3];
    const float* C       = (const float*)d_in[4];
    const float* D       = (const float*)d_in[5];
    const float* z       = (const float*)d_in[6];
    const float* dt_bias = (const float*)d_in[7];

    float* out           = (float*)d_out;
    float* final_states  = out + (size_t)BATCH * SEQ * NH * HD;

    float* ws       = (float*)d_ws;
    float* dtp      = ws;                                    // 262144 f
    float* dacs     = dtp + 262144;                          // 262144 f
    float* states   = dacs + 262144;                         // 8388608 f
    unsigned* cb_bf = (unsigned*)(states + 8388608);         // 524288 dw
    unsigned* xT    = cb_bf + 524288;                        // 8388608 dw  (B*NC*NH*64*128)
    unsigned* BT    = xT + 8388608;                          // 262144 dw
    unsigned* Cb    = BT + 262144;                           // 262144 dw
    // total: 18,350,080 dwords = 73.4 MB

    k0a_xT  <<<BATCH * NC * NH, 256, 0, stream>>>(x, xT);
    k0b_cast<<<256,             256, 0, stream>>>(C, Cb);
    k0c_BT  <<<BATCH * NC * 8,  256, 0, stream>>>(B, BT);
    k1_dt   <<<BATCH * NH * NC, CS,  0, stream>>>(dt, A, dt_bias, dtp, dacs);
    k2_cb   <<<BATCH * NC * 10, 256, 0, stream>>>(B, C, cb_bf);
    k3_chunk_state<<<BATCH * NC * NH, 256, 0, stream>>>(xT, BT, dtp, dacs, states);
    k4_state_passing<<<(BATCH * NH * HD * DS) / 256, 256, 0, stream>>>(states, dacs, final_states);
    k5_chunk_scan<<<BATCH * NC * NH, 256, 0, stream>>>(x, z, Cb, D, dtp, dacs,
                                                       cb_bf, xT, states, out);
}

// Round 6
// 336.079 us; speedup vs baseline: 1.7992x; 1.1851x over previous
//
#include <hip/hip_runtime.h>
#include <math.h>

#define BATCH 2
#define SEQ   2048
#define NH    64
#define HD    64
#define DS    128
#define CS    256
#define NC    8   // SEQ/CS

typedef __attribute__((ext_vector_type(8))) short s16x8;   // 8 bf16 (4 VGPR)
typedef __attribute__((ext_vector_type(4))) float f32x4;   // 16x16 acc

#define MFMA16(a,b,c) __builtin_amdgcn_mfma_f32_16x16x32_bf16(a, b, c, 0, 0, 0)

// explicit RNE f32->bf16
__device__ inline unsigned short f2bf(float f) {
    unsigned u = __float_as_uint(f);
    return (unsigned short)((u + (0x7fffu + ((u >> 16) & 1u))) >> 16);
}
__device__ inline unsigned pack2bf(float a, float b) {
    return (unsigned)f2bf(a) | ((unsigned)f2bf(b) << 16);
}
__device__ inline float2 unpack2bf(unsigned u) {
    return make_float2(__uint_as_float(u << 16), __uint_as_float(u & 0xffff0000u));
}

union frag_u { unsigned u[4]; s16x8 v; };

// ---------------------------------------------------------------------------
// K1: dt softplus + dA cumsum (fp32).  dtp/dacs: ((b*NH+h)*NC+c)*CS + s
// ---------------------------------------------------------------------------
__global__ __launch_bounds__(CS) void k1_dt(
    const float* __restrict__ dt, const float* __restrict__ A,
    const float* __restrict__ dt_bias,
    float* __restrict__ dtp, float* __restrict__ dacs)
{
    int bid = blockIdx.x;                 // ((b*NH+h)*NC+c)
    int c = bid % NC;
    int h = (bid / NC) % NH;
    int b = bid / (NC * NH);
    int s = threadIdx.x;

    float v  = dt[((size_t)b * SEQ + c * CS + s) * NH + h] + dt_bias[h];
    float sp = fmaxf(v, 0.f) + log1pf(__expf(-fabsf(v)));
    float dA = sp * A[h];

    __shared__ float sm[CS];
    sm[s] = dA;
    __syncthreads();
    for (int off = 1; off < CS; off <<= 1) {
        float tt = (s >= off) ? sm[s - off] : 0.f;
        __syncthreads();
        sm[s] += tt;
        __syncthreads();
    }
    size_t o = (size_t)bid * CS + s;
    dtp[o]  = sp;
    dacs[o] = sm[s];
}

// ---------------------------------------------------------------------------
// K0a: xdt[(b,c,h), p, s] = bf16( x[b,s,h,p] * dtp[s] ).  1024 blocks.
// ---------------------------------------------------------------------------
__global__ __launch_bounds__(256) void k0a_xdt(
    const float* __restrict__ x, const float* __restrict__ dtp,
    unsigned* __restrict__ xdt)
{
    int bid = blockIdx.x;             // ((b*NC+c)*NH+h)
    int h = bid & 63, c = (bid >> 6) & 7, b = bid >> 9;
    int t = threadIdx.x;
    size_t dt_base = ((size_t)(b*NH + h)*NC + c)*CS;
    __shared__ float tile[64][65];
    __shared__ float dtS[64];
    for (int st = 0; st < 4; ++st) {
        int s0 = st * 64;
        __syncthreads();
        if (t < 64) dtS[t] = dtp[dt_base + s0 + t];
        #pragma unroll
        for (int i = 0; i < 16; ++i) {
            int f = t + i * 256;
            int row = f >> 6, col = f & 63;
            tile[row][col] = x[((size_t)(b*SEQ + c*CS + s0 + row)*NH + h)*HD + col];
        }
        __syncthreads();
        #pragma unroll
        for (int i = 0; i < 8; ++i) {
            int f = t + i * 256;
            int p = f >> 5, sd = f & 31;
            xdt[((size_t)bid*64 + p)*128 + (s0 >> 1) + sd] =
                pack2bf(tile[2*sd][p] * dtS[2*sd], tile[2*sd+1][p] * dtS[2*sd+1]);
        }
    }
}

// ---------------------------------------------------------------------------
// K0b: flat f32 -> packed bf16 cast (for C). 256 blocks x 256 thr x 8 elems.
// ---------------------------------------------------------------------------
__global__ __launch_bounds__(256) void k0b_cast(
    const float* __restrict__ src, unsigned* __restrict__ dst)
{
    size_t f = (size_t)blockIdx.x * 256 + threadIdx.x;
    const float4* s4 = (const float4*)(src + f * 8);
    float4 a = s4[0], bq = s4[1];
    uint4 o;
    o.x = pack2bf(a.x,  a.y);  o.y = pack2bf(a.z,  a.w);
    o.z = pack2bf(bq.x, bq.y); o.w = pack2bf(bq.z, bq.w);
    *(uint4*)(dst + f * 4) = o;
}

// ---------------------------------------------------------------------------
// K0c: B[b,s,n] f32 -> BT[(b,c), n, s] bf16. 128 blocks (bc*8 + nt*4 + st).
// ---------------------------------------------------------------------------
__global__ __launch_bounds__(256) void k0c_BT(
    const float* __restrict__ Bg, unsigned* __restrict__ BT)
{
    int bid = blockIdx.x;
    int st = bid & 3, nt = (bid >> 2) & 1, bc = bid >> 3;
    int b = bc >> 3, c = bc & 7;
    int s0 = st * 64, n0 = nt * 64;
    int t = threadIdx.x;
    __shared__ float tile[64][65];
    #pragma unroll
    for (int i = 0; i < 16; ++i) {
        int f = t + i * 256;
        int row = f >> 6, col = f & 63;
        tile[row][col] = Bg[(size_t)(b*SEQ + c*CS + s0 + row)*DS + n0 + col];
    }
    __syncthreads();
    #pragma unroll
    for (int i = 0; i < 8; ++i) {
        int f = t + i * 256;
        int n = f >> 5, sd = f & 31;
        BT[((size_t)bc*128 + n0 + n)*128 + (s0 >> 1) + sd] =
            pack2bf(tile[2*sd][n], tile[2*sd+1][n]);
    }
}

// ---------------------------------------------------------------------------
// K2: CB tiles (fp32 VALU compute, bf16 packed output). Only tl >= ts tiles.
// grid = B*NC*10.
// ---------------------------------------------------------------------------
__global__ __launch_bounds__(256) void k2_cb(
    const float* __restrict__ Bg_, const float* __restrict__ Cg_,
    unsigned* __restrict__ cb_bf)
{
    const int TLt[10] = {0,1,1,2,2,2,3,3,3,3};
    const int TSt[10] = {0,0,1,0,1,2,0,1,2,3};
    int bid = blockIdx.x;
    int ti = bid % 10;
    int bc = bid / 10;
    int tl = TLt[ti], ts = TSt[ti];
    int b = bc / NC, c = bc % NC;

    const float* Cg = Cg_ + (size_t)(b * SEQ + c * CS + tl * 64) * DS;
    const float* Bg = Bg_ + (size_t)(b * SEQ + c * CS + ts * 64) * DS;

    __shared__ __align__(16) float Ct[32][68];
    __shared__ __align__(16) float Bt[32][68];

    int t  = threadIdx.x;
    int tx = t & 15, ty = t >> 4;
    int s0 = tx * 4, l0 = ty * 4;
    float acc[4][4] = {};

    for (int n0 = 0; n0 < DS; n0 += 32) {
        __syncthreads();
        {
            int r  = t >> 5;
            int nn = t & 31;
            #pragma unroll
            for (int i = 0; i < 8; ++i) {
                Ct[nn][r + i * 8] = Cg[(size_t)(r + i * 8) * DS + n0 + nn];
                Bt[nn][r + i * 8] = Bg[(size_t)(r + i * 8) * DS + n0 + nn];
            }
        }
        __syncthreads();
        #pragma unroll 8
        for (int n = 0; n < 32; ++n) {
            float4 cv = *(const float4*)&Ct[n][l0];
            float4 bv = *(const float4*)&Bt[n][s0];
            float cva[4] = {cv.x, cv.y, cv.z, cv.w};
            float bva[4] = {bv.x, bv.y, bv.z, bv.w};
            #pragma unroll
            for (int i = 0; i < 4; ++i)
                #pragma unroll
                for (int j = 0; j < 4; ++j)
                    acc[i][j] += cva[i] * bva[j];
        }
    }

    unsigned* cbg = cb_bf + (size_t)bc * 32768;   // 256*128 dwords
    #pragma unroll
    for (int i = 0; i < 4; ++i) {
        int row  = tl * 64 + l0 + i;
        int colb = (ts * 64 + s0) >> 1;
        uint2 wv;
        wv.x = pack2bf(acc[i][0], acc[i][1]);
        wv.y = pack2bf(acc[i][2], acc[i][3]);
        *(uint2*)&cbg[(size_t)row * 128 + colb] = wv;
    }
}

// ---------------------------------------------------------------------------
// K3: chunk_state, fragment-direct. grid = B*NC*NH, 4 waves; wave w owns
// p-tile w. A = xdt * exp(daL - dacs[s]) computed in registers; B = BT direct.
// Output states_bf[(b,c,h)][p][n] bf16.
// ---------------------------------------------------------------------------
__global__ __launch_bounds__(256) void k3_chunk_state(
    const unsigned* __restrict__ xdt, const unsigned* __restrict__ BT,
    const float* __restrict__ dacs, unsigned short* __restrict__ states_bf)
{
    int bid = blockIdx.x;                 // ((b*NC+c)*NH+h)
    int bc = bid >> 6;
    int h = bid & 63, c = (bid >> 6) & 7, b = bid >> 9;
    int t = threadIdx.x;
    int w = t >> 6, lane = t & 63, m16 = lane & 15, q = lane >> 4;

    size_t dt_base = ((size_t)(b*NH + h)*NC + c)*CS;
    __shared__ float coS[CS];
    {
        float daL = dacs[dt_base + CS - 1];
        coS[t] = __expf(daL - dacs[dt_base + t]);
    }
    __syncthreads();

    const unsigned* xb = xdt + (size_t)bid * 8192;
    const unsigned* bb = BT + (size_t)bc * 16384;

    f32x4 acc[8] = {};

    #pragma unroll
    for (int ks = 0; ks < 4; ++ks) {
        #pragma unroll
        for (int kk = 0; kk < 2; ++kk) {
            int kd = ks*32 + kk*16 + q*4;
            int sbase = ks*64 + kk*32 + q*8;
            uint4 xq = *(const uint4*)&xb[(w*16 + m16)*128 + kd];
            float co8[8];
            *(float4*)&co8[0] = *(const float4*)&coS[sbase];
            *(float4*)&co8[4] = *(const float4*)&coS[sbase + 4];
            frag_u af;
            {
                float2 v0 = unpack2bf(xq.x), v1 = unpack2bf(xq.y);
                float2 v2 = unpack2bf(xq.z), v3 = unpack2bf(xq.w);
                af.u[0] = pack2bf(v0.x*co8[0], v0.y*co8[1]);
                af.u[1] = pack2bf(v1.x*co8[2], v1.y*co8[3]);
                af.u[2] = pack2bf(v2.x*co8[4], v2.y*co8[5]);
                af.u[3] = pack2bf(v3.x*co8[6], v3.y*co8[7]);
            }
            #pragma unroll
            for (int nt = 0; nt < 8; ++nt) {
                s16x8 bf8 = *(const s16x8*)&bb[(nt*16 + m16)*128 + kd];
                acc[nt] = MFMA16(af.v, bf8, acc[nt]);
            }
        }
    }

    unsigned short* sg = states_bf + (size_t)bid * 8192;
    #pragma unroll
    for (int nt = 0; nt < 8; ++nt) {
        #pragma unroll
        for (int r = 0; r < 4; ++r) {
            int p = w*16 + q*4 + r;
            sg[p*128 + nt*16 + m16] = f2bf(acc[nt][r]);
        }
    }
}

// ---------------------------------------------------------------------------
// K4: state_passing. Reads states_bf (as dword pairs), fp32 recurrence across
// chunks, writes prevT bf16 pairs + final_states fp32.
// ---------------------------------------------------------------------------
__global__ __launch_bounds__(256) void k4_state_passing(
    const unsigned* __restrict__ states_bf, const float* __restrict__ dacs,
    unsigned* __restrict__ prevT, float* __restrict__ final_states)
{
    int e = blockIdx.x * 256 + threadIdx.x;   // over B*NH*HD*DS/2 = 524288
    int n2 = e & 63;
    int p  = (e >> 6) & 63;
    int h  = (e >> 12) & 63;
    int b  = e >> 18;

    float r0 = 0.f, r1 = 0.f;
    #pragma unroll
    for (int c = 0; c < NC; ++c) {
        size_t idx = (((size_t)(b*NC + c)*NH + h)*HD + p)*64 + n2;
        float2 vv = unpack2bf(states_bf[idx]);
        prevT[idx] = pack2bf(r0, r1);
        float el = __expf(dacs[((size_t)(b*NH + h)*NC + c)*CS + CS - 1]);
        r0 = el * r0 + vv.x;
        r1 = el * r1 + vv.y;
    }
    float* fg = final_states + (((size_t)(b*NH + h)*HD + p)*DS + 2*n2);
    fg[0] = r0; fg[1] = r1;
}

// ---------------------------------------------------------------------------
// K5: chunk_scan, fragment-direct, no mid-kernel barriers. grid = B*NC*NH,
// 4 waves. Wave w owns interleaved 16-row l-tiles {w, w+4, w+8, w+12}
// (balanced triangle). Phase B: A = cb*decay masked in regs (cb global,
// shared across h -> L2); B = xdt direct. Phase A: A = Cb*exp(dacs[l]),
// B = prevT direct; shared accumulator. Epilogue fused.
// ---------------------------------------------------------------------------
__global__ __launch_bounds__(256) void k5_chunk_scan(
    const float* __restrict__ x, const float* __restrict__ z,
    const unsigned* __restrict__ Cb, const float* __restrict__ Dp,
    const float* __restrict__ dacs, const unsigned* __restrict__ cb_bf,
    const unsigned* __restrict__ xdt, const unsigned* __restrict__ prevT,
    float* __restrict__ out)
{
    int bid = blockIdx.x;                 // ((b*NC+c)*NH+h)
    int h = bid & 63, c = (bid >> 6) & 7, b = bid >> 9;
    int bc = bid >> 6;
    int t = threadIdx.x;
    int w = t >> 6, lane = t & 63, m16 = lane & 15, q = lane >> 4;

    __shared__ float dacsS[CS];
    __shared__ float elS[CS];
    size_t dt_base = ((size_t)(b*NH + h)*NC + c)*CS;
    {
        float dv = dacs[dt_base + t];
        dacsS[t] = dv;
        elS[t]   = __expf(dv);
    }
    __syncthreads();

    const unsigned* xb  = xdt + (size_t)bid * 8192;
    const unsigned* cbb = cb_bf + (size_t)bc * 32768;

    f32x4 acc[4][4] = {};                 // [jj][pt]; l-tile jj -> rows (w+4jj)*16
    float dlv[4];
    #pragma unroll
    for (int jj = 0; jj < 4; ++jj) dlv[jj] = dacsS[(w + 4*jj)*16 + m16];

    // ---- phase B: intra-chunk masked scan ----
    #pragma unroll
    for (int st = 0; st < 4; ++st) {
        int s0 = st * 64;
        #pragma unroll
        for (int kk = 0; kk < 2; ++kk) {
            int kd = (s0 >> 1) + kk*16 + q*4;
            s16x8 bfr[4];
            #pragma unroll
            for (int pt = 0; pt < 4; ++pt)
                bfr[pt] = *(const s16x8*)&xb[(pt*16 + m16)*128 + kd];
            int sbase = s0 + kk*32 + q*8;
            float ds8[8];
            *(float4*)&ds8[0] = *(const float4*)&dacsS[sbase];
            *(float4*)&ds8[4] = *(const float4*)&dacsS[sbase + 4];
            #pragma unroll
            for (int jj = st; jj < 4; ++jj) {
                // diagonal fully-masked sub-tile for wave 0:
                if (st == jj && kk == 1 && w == 0) continue;
                int lrow = (w + 4*jj)*16 + m16;    // chunk-local l
                float dl = dlv[jj];
                uint4 cbq = *(const uint4*)&cbb[(size_t)lrow*128 + kd];
                frag_u af;
                float2 v0 = unpack2bf(cbq.x), v1 = unpack2bf(cbq.y);
                float2 v2 = unpack2bf(cbq.z), v3 = unpack2bf(cbq.w);
                float wv[8];
                wv[0] = v0.x * __expf(dl - ds8[0]);
                wv[1] = v0.y * __expf(dl - ds8[1]);
                wv[2] = v1.x * __expf(dl - ds8[2]);
                wv[3] = v1.y * __expf(dl - ds8[3]);
                wv[4] = v2.x * __expf(dl - ds8[4]);
                wv[5] = v2.y * __expf(dl - ds8[5]);
                wv[6] = v3.x * __expf(dl - ds8[6]);
                wv[7] = v3.y * __expf(dl - ds8[7]);
                if (st == jj) {                    // diagonal: apply causal mask
                    #pragma unroll
                    for (int j = 0; j < 8; ++j)
                        wv[j] = (sbase + j <= lrow) ? wv[j] : 0.f;
                }
                af.u[0] = pack2bf(wv[0], wv[1]);
                af.u[1] = pack2bf(wv[2], wv[3]);
                af.u[2] = pack2bf(wv[4], wv[5]);
                af.u[3] = pack2bf(wv[6], wv[7]);
                #pragma unroll
                for (int pt = 0; pt < 4; ++pt)
                    acc[jj][pt] = MFMA16(af.v, bfr[pt], acc[jj][pt]);
            }
        }
    }

    // ---- phase A: inter-chunk term, decay folded into C-fragment ----
    {
        const unsigned* pb = prevT + (size_t)bid * 4096;
        float elv[4];
        #pragma unroll
        for (int jj = 0; jj < 4; ++jj) elv[jj] = elS[(w + 4*jj)*16 + m16];
        #pragma unroll
        for (int kq = 0; kq < 4; ++kq) {
            int kd = kq*16 + q*4;
            s16x8 pfr[4];
            #pragma unroll
            for (int pt = 0; pt < 4; ++pt)
                pfr[pt] = *(const s16x8*)&pb[(pt*16 + m16)*64 + kd];
            #pragma unroll
            for (int jj = 0; jj < 4; ++jj) {
                int lrow = (w + 4*jj)*16 + m16;
                uint4 cq = *(const uint4*)&Cb[(size_t)(b*SEQ + c*CS + lrow)*64 + kd];
                float el = elv[jj];
                frag_u af;
                float2 v0 = unpack2bf(cq.x), v1 = unpack2bf(cq.y);
                float2 v2 = unpack2bf(cq.z), v3 = unpack2bf(cq.w);
                af.u[0] = pack2bf(v0.x*el, v0.y*el);
                af.u[1] = pack2bf(v1.x*el, v1.y*el);
                af.u[2] = pack2bf(v2.x*el, v2.y*el);
                af.u[3] = pack2bf(v3.x*el, v3.y*el);
                #pragma unroll
                for (int pt = 0; pt < 4; ++pt)
                    acc[jj][pt] = MFMA16(af.v, pfr[pt], acc[jj][pt]);
            }
        }
    }

    // ---- epilogue: + x*D, SiLU(z) gate ----
    float Dh = Dp[h];
    #pragma unroll
    for (int jj = 0; jj < 4; ++jj) {
        #pragma unroll
        for (int r = 0; r < 4; ++r) {
            int l = (w + 4*jj)*16 + q*4 + r;
            size_t gro = ((size_t)(b*SEQ + c*CS + l)*NH + h)*HD;
            #pragma unroll
            for (int pt = 0; pt < 4; ++pt) {
                int p = pt*16 + m16;
                float xv = x[gro + p], zv = z[gro + p];
                float o = acc[jj][pt][r] + xv * Dh;
                float sig = 1.f / (1.f + __expf(-zv));
                out[gro + p] = o * (zv * sig);
            }
        }
    }
}

// ---------------------------------------------------------------------------
extern "C" void kernel_launch(void* const* d_in, const int* in_sizes, int n_in,
                              void* d_out, int out_size, void* d_ws, size_t ws_size,
                              hipStream_t stream)
{
    (void)in_sizes; (void)n_in; (void)out_size; (void)ws_size;
    const float* x       = (const float*)d_in[0];
    const float* dt      = (const float*)d_in[1];
    const float* A       = (const float*)d_in[2];
    const float* B       = (const float*)d_in[3];
    const float* C       = (const float*)d_in[4];
    const float* D       = (const float*)d_in[5];
    const float* z       = (const float*)d_in[6];
    const float* dt_bias = (const float*)d_in[7];

    float* out           = (float*)d_out;
    float* final_states  = out + (size_t)BATCH * SEQ * NH * HD;

    float* ws        = (float*)d_ws;
    float* dtp       = ws;                                   // 262144 f
    float* dacs      = dtp + 262144;                         // 262144 f
    unsigned short* states_bf = (unsigned short*)(dacs + 262144); // 8388608 u16 = 4194304 dw
    unsigned* prevT  = (unsigned*)(states_bf + 8388608);     // 4194304 dw
    unsigned* cb_bf  = prevT + 4194304;                      // 524288 dw
    unsigned* xdt    = cb_bf + 524288;                       // 8388608 dw
    unsigned* BT     = xdt + 8388608;                        // 262144 dw
    unsigned* Cb     = BT + 262144;                          // 262144 dw
    // total: 18,350,080 dwords = 73.4 MB (same as known-good round 4)

    k1_dt   <<<BATCH * NH * NC, CS,  0, stream>>>(dt, A, dt_bias, dtp, dacs);
    k0a_xdt <<<BATCH * NC * NH, 256, 0, stream>>>(x, dtp, xdt);
    k0b_cast<<<256,             256, 0, stream>>>(C, Cb);
    k0c_BT  <<<BATCH * NC * 8,  256, 0, stream>>>(B, BT);
    k2_cb   <<<BATCH * NC * 10, 256, 0, stream>>>(B, C, cb_bf);
    k3_chunk_state<<<BATCH * NC * NH, 256, 0, stream>>>(xdt, BT, dacs, states_bf);
    k4_state_passing<<<(BATCH * NH * HD * DS / 2) / 256, 256, 0, stream>>>(
        (const unsigned*)states_bf, dacs, prevT, final_states);
    k5_chunk_scan<<<BATCH * NC * NH, 256, 0, stream>>>(x, z, Cb, D, dacs,
                                                       cb_bf, xdt, prevT, out);
}